// Round 12
// baseline (193.114 us; speedup 1.0000x reference)
//
#include <hip/hip_runtime.h>
#include <hip/hip_fp16.h>

// GCN layer on MI355X — CSR-gather, atomic-free CSR build, fp16 MFMA GEMM.
// out[c] = dis[c] * ( sum_{e: dst=c} t2[src_e] + t2[c] ) + bias
// t2[i] = dis[i] * (x @ W)[i], dis[i] = rsqrt(1 + outdeg(i)).
//
// Round-11 post-mortem (100.2us): gather (~40us) is bound by L2-miss traffic
// = 8 XCDs x 12.8MB table (~93MB) — every XCD fills the whole t2h into its
// private L2 because sources are random. This round: XCD-PARTITIONED gather —
// grid (node-group, slice k=blockIdx%8); under round-robin dispatch all
// slice-k blocks land on XCD k, so each L2 caches only a 32B/row column
// slice (1.6MB, L2-resident). Cold fill ~13MB vs 93MB. Correctness does not
// depend on the mapping (wrong mapping = today's perf, not wrong results).

#define EPB 4096  // edges per k_hist/k_part block

typedef _Float16 f16;
typedef f16 f16x8 __attribute__((ext_vector_type(8)));
typedef float f32x4 __attribute__((ext_vector_type(4)));

static inline int cdiv(int a, int b) { return (a + b - 1) / b; }

// P1: coarse histograms, transposed layout hist[bin*nblk + blk] (dst) and
// hist[HALF + bin*nblk + blk] (src), HALF = nbins*nblk.
// Blocks 0..63 also transpose W -> WhT fp16 (256 elems each, parallel).
__global__ __launch_bounds__(256) void k_hist(const int* __restrict__ ei, int E,
                                              int* __restrict__ hist, int nblk, int nbins,
                                              const float* __restrict__ W,
                                              f16* __restrict__ WhT) {
  __shared__ int ha[256], hb[256];
  const int tid = threadIdx.x, blk = blockIdx.x;
  ha[tid] = 0; hb[tid] = 0;
  __syncthreads();
  const int base = blk * EPB;
  const int lim = min(EPB, E - base);
  if ((E & 3) == 0) {
    for (int i = tid * 4; i + 3 < lim; i += 1024) {
      int4 s4 = *(const int4*)(ei + base + i);
      int4 d4 = *(const int4*)(ei + E + base + i);
      atomicAdd(&ha[d4.x >> 8], 1); atomicAdd(&hb[s4.x >> 8], 1);
      atomicAdd(&ha[d4.y >> 8], 1); atomicAdd(&hb[s4.y >> 8], 1);
      atomicAdd(&ha[d4.z >> 8], 1); atomicAdd(&hb[s4.z >> 8], 1);
      atomicAdd(&ha[d4.w >> 8], 1); atomicAdd(&hb[s4.w >> 8], 1);
    }
    for (int i = (lim & ~3) + tid; i < lim; i += 256) {
      atomicAdd(&ha[ei[E + base + i] >> 8], 1);
      atomicAdd(&hb[ei[base + i] >> 8], 1);
    }
  } else {
    for (int i = tid; i < lim; i += 256) {
      atomicAdd(&ha[ei[E + base + i] >> 8], 1);
      atomicAdd(&hb[ei[base + i] >> 8], 1);
    }
  }
  if (blk < 64) {  // W[k][c] -> WhT[c][k], 64 blocks x 256 = 16384 elems
    int i = blk * 256 + tid;
    int k = i >> 7, c = i & 127;
    WhT[c * 128 + k] = (f16)W[i];
  }
  __syncthreads();
  if (tid < nbins) {
    hist[tid * nblk + blk] = ha[tid];
    hist[nbins * nblk + tid * nblk + blk] = hb[tid];
  }
}

// Hierarchical exclusive scan stage 1 (in place), 1024 elems/block.
// partials keeps RAW block sums; consumers scan them in LDS themselves.
__global__ __launch_bounds__(256) void k_scan1(int* __restrict__ a,
                                               int* __restrict__ partials, int M) {
  __shared__ int ws[256];
  const int tid = threadIdx.x;
  const int i0 = blockIdx.x * 1024 + tid * 4;
  int v0 = (i0 + 0 < M) ? a[i0 + 0] : 0;
  int v1 = (i0 + 1 < M) ? a[i0 + 1] : 0;
  int v2 = (i0 + 2 < M) ? a[i0 + 2] : 0;
  int v3 = (i0 + 3 < M) ? a[i0 + 3] : 0;
  int tsum = v0 + v1 + v2 + v3;
  ws[tid] = tsum;
  __syncthreads();
#pragma unroll
  for (int off = 1; off < 256; off <<= 1) {
    int add = (tid >= off) ? ws[tid - off] : 0;
    __syncthreads();
    ws[tid] += add;
    __syncthreads();
  }
  int texcl = ws[tid] - tsum;
  if (tid == 255) partials[blockIdx.x] = ws[255];
  if (i0 + 0 < M) a[i0 + 0] = texcl;
  if (i0 + 1 < M) a[i0 + 1] = texcl + v0;
  if (i0 + 2 < M) a[i0 + 2] = texcl + v0 + v1;
  if (i0 + 3 < M) a[i0 + 3] = texcl + v0 + v1 + v2;
}

// Shared helper: exclusive-scan nb1 (<=256) raw partials into shP.
__device__ __forceinline__ void scan_partials(const int* __restrict__ partials,
                                              int nb1, int* shP, int tid) {
  int v = (tid < nb1) ? partials[tid] : 0;
  shP[tid] = v;
  __syncthreads();
#pragma unroll
  for (int off = 1; off < 256; off <<= 1) {
    int add = (tid >= off) ? shP[tid - off] : 0;
    __syncthreads();
    shP[tid] += add;
    __syncthreads();
  }
  int excl = shP[tid] - v;
  __syncthreads();
  shP[tid] = excl;
  __syncthreads();
}

// P2: partition edges into coarse buckets. ebA[posA] = (src<<8)|(dst&255)
// (dst-bucketed), ebB[posB] = src&255 (src-bucketed, uchar). Plain stores only.
__global__ __launch_bounds__(256) void k_part(const int* __restrict__ ei, int E,
                                              const int* __restrict__ hist,
                                              const int* __restrict__ partials, int nb1,
                                              int nblk, int nbins,
                                              int* __restrict__ ebA,
                                              unsigned char* __restrict__ ebB) {
  __shared__ int cA[256], cB[256], shP[256];
  const int tid = threadIdx.x, blk = blockIdx.x;
  const int HALF = nbins * nblk;
  scan_partials(partials, nb1, shP, tid);
  if (tid < nbins) {
    int ia = tid * nblk + blk;
    int ib = HALF + tid * nblk + blk;
    cA[tid] = hist[ia] + shP[ia >> 10];
    cB[tid] = hist[ib] + shP[ib >> 10] - E;
  }
  __syncthreads();
  const int base = blk * EPB;
  const int lim = min(EPB, E - base);
  if ((E & 3) == 0) {
    for (int i = tid * 4; i + 3 < lim; i += 1024) {
      int4 s4 = *(const int4*)(ei + base + i);
      int4 d4 = *(const int4*)(ei + E + base + i);
      int pa, pb;
      pa = atomicAdd(&cA[d4.x >> 8], 1); ebA[pa] = (s4.x << 8) | (d4.x & 255);
      pb = atomicAdd(&cB[s4.x >> 8], 1); ebB[pb] = (unsigned char)(s4.x & 255);
      pa = atomicAdd(&cA[d4.y >> 8], 1); ebA[pa] = (s4.y << 8) | (d4.y & 255);
      pb = atomicAdd(&cB[s4.y >> 8], 1); ebB[pb] = (unsigned char)(s4.y & 255);
      pa = atomicAdd(&cA[d4.z >> 8], 1); ebA[pa] = (s4.z << 8) | (d4.z & 255);
      pb = atomicAdd(&cB[s4.z >> 8], 1); ebB[pb] = (unsigned char)(s4.z & 255);
      pa = atomicAdd(&cA[d4.w >> 8], 1); ebA[pa] = (s4.w << 8) | (d4.w & 255);
      pb = atomicAdd(&cB[s4.w >> 8], 1); ebB[pb] = (unsigned char)(s4.w & 255);
    }
    for (int i = (lim & ~3) + tid; i < lim; i += 256) {
      int s = ei[base + i], d = ei[E + base + i];
      int pa = atomicAdd(&cA[d >> 8], 1); ebA[pa] = (s << 8) | (d & 255);
      int pb = atomicAdd(&cB[s >> 8], 1); ebB[pb] = (unsigned char)(s & 255);
    }
  } else {
    for (int i = tid; i < lim; i += 256) {
      int s = ei[base + i], d = ei[E + base + i];
      int pa = atomicAdd(&cA[d >> 8], 1); ebA[pa] = (s << 8) | (d & 255);
      int pb = atomicAdd(&cB[s >> 8], 1); ebB[pb] = (unsigned char)(s & 255);
    }
  }
}

// P3 merged: per coarse bucket b,
//  phase 1 (deg): fine count of src over ebB bucket -> dis = rsqrt(1+cnt)
//  phase 2 (csr): fine count+scan of dst over ebA bucket -> offs, place srcs
// srcs stored PRE-SCALED by 64 (half2-row units) for the gather.
__global__ __launch_bounds__(256) void k_bucket(
    const int* __restrict__ ebA, const unsigned char* __restrict__ ebB,
    const int* __restrict__ hist, const int* __restrict__ partials, int nb1,
    int nblk, int nbins, int E,
    float* __restrict__ dis, int* __restrict__ offs,
    int* __restrict__ srcs, int N) {
  __shared__ int h[256], tmp[256], cur[256], shP[256];
  const int tid = threadIdx.x, b = blockIdx.x;
  const int HALF = nbins * nblk;
  const int node = b * 256 + tid;
  scan_partials(partials, nb1, shP, tid);

  // --- phase 1: out-degree -> dis ---
  {
    int i0 = HALF + b * nblk;
    const int bs = hist[i0] + shP[i0 >> 10] - E;
    int be = E;
    if (b + 1 < nbins) {
      int i1 = HALF + (b + 1) * nblk;
      be = hist[i1] + shP[i1 >> 10] - E;
    }
    h[tid] = 0;
    __syncthreads();
    for (int j = bs + tid; j < be; j += 256) atomicAdd(&h[ebB[j]], 1);
    __syncthreads();
    if (node < N) dis[node] = rsqrtf(1.0f + (float)h[tid]);
    __syncthreads();
  }

  // --- phase 2: CSR offs + srcs ---
  {
    int i0 = b * nblk;
    const int bs = hist[i0] + shP[i0 >> 10];
    int be = E;
    if (b + 1 < nbins) {
      int i1 = (b + 1) * nblk;
      be = hist[i1] + shP[i1 >> 10];
    }
    h[tid] = 0;
    __syncthreads();
    for (int j = bs + tid; j < be; j += 256) atomicAdd(&h[ebA[j] & 255], 1);
    __syncthreads();
    int cnt = h[tid];
    tmp[tid] = cnt;
    __syncthreads();
#pragma unroll
    for (int off = 1; off < 256; off <<= 1) {
      int add = (tid >= off) ? tmp[tid - off] : 0;
      __syncthreads();
      tmp[tid] += add;
      __syncthreads();
    }
    int gpos = bs + tmp[tid] - cnt;
    if (node < N) offs[node] = gpos;
    cur[tid] = gpos;
    __syncthreads();
    for (int j = bs + tid; j < be; j += 256) {
      int v = ebA[j];
      int p = atomicAdd(&cur[v & 255], 1);
      srcs[p] = (v >> 8) << 6;  // pre-scaled: src * 64 half2-units
    }
    if (b == 0 && tid == 0) offs[N] = E;
  }
}

// MFMA GEMM: t2h[r][c] = fp16( dis[r] * sum_k x[r][k] * W[k][c] ).
// 256 thr = 4 waves; wave w owns rows [blk*64 + w*16, +16), all 128 cols.
// Per wave: 8 col-tiles x 4 k-chunks of mfma_f32_16x16x32_f16.
// C/D layout: col = lane&15, row = (lane>>4)*4 + reg  [guide §3, m89].
__global__ __launch_bounds__(256) void k_gemm_mfma(
    const float* __restrict__ x, const f16* __restrict__ WhT,
    const float* __restrict__ dis, __half* __restrict__ t2h, int N) {
  __shared__ __align__(16) f16 cs[4][16][136];  // stride 272B = 17x16B
  const int tid = threadIdx.x;
  const int w = tid >> 6, l = tid & 63;
  const int l15 = l & 15, lg = l >> 4;
  const int wr0 = blockIdx.x * 64 + w * 16;
  const int arow = wr0 + l15;
  const bool avalid = arow < N;

  f32x4 acc[8];
#pragma unroll
  for (int ct = 0; ct < 8; ++ct) acc[ct] = (f32x4){0.f, 0.f, 0.f, 0.f};

#pragma unroll
  for (int kc = 0; kc < 4; ++kc) {
    f16x8 af;
    if (avalid) {
      const float4* ap = (const float4*)(x + (size_t)arow * 128 + kc * 32 + lg * 8);
      float4 a0 = ap[0], a1 = ap[1];
      af[0] = (f16)a0.x; af[1] = (f16)a0.y; af[2] = (f16)a0.z; af[3] = (f16)a0.w;
      af[4] = (f16)a1.x; af[5] = (f16)a1.y; af[6] = (f16)a1.z; af[7] = (f16)a1.w;
    } else {
#pragma unroll
      for (int j = 0; j < 8; ++j) af[j] = (f16)0.f;
    }
#pragma unroll
    for (int ct = 0; ct < 8; ++ct) {
      f16x8 bf = *(const f16x8*)(WhT + (ct * 16 + l15) * 128 + kc * 32 + lg * 8);
      acc[ct] = __builtin_amdgcn_mfma_f32_16x16x32_f16(af, bf, acc[ct], 0, 0, 0);
    }
  }

  // scale rows by dis and stash (transposed per-wave) in LDS
  float d4[4];
#pragma unroll
  for (int j = 0; j < 4; ++j) {
    int r = wr0 + lg * 4 + j;
    d4[j] = (r < N) ? dis[r] : 0.f;
  }
#pragma unroll
  for (int ct = 0; ct < 8; ++ct)
#pragma unroll
    for (int j = 0; j < 4; ++j)
      cs[w][lg * 4 + j][ct * 16 + l15] = (f16)(d4[j] * acc[ct][j]);
  __syncthreads();

  // coalesced write-out: 4 iters x 64 lanes x 16B
#pragma unroll
  for (int it = 0; it < 4; ++it) {
    int t = it * 64 + l;
    int row = t >> 4, seg = t & 15;
    int gr = wr0 + row;
    if (gr < N)
      *(f16x8*)((f16*)t2h + (size_t)gr * 128 + seg * 8) = *(const f16x8*)&cs[w][row][seg * 8];
  }
}

// XCD-partitioned gather. Grid = (node-group g) x (slice k = blockIdx&7).
// Under round-robin dispatch all slice-k blocks land on XCD k, whose L2 then
// caches only t2h columns [k*16, k*16+16) — 1.6MB, L2-resident.
// Wave = one node: lane l -> (phase ph=l>>3 over edges, col c=l&7 within
// slice). Per edge: 8 lanes x 4B = 32B segment. shfl_xor(8/16/32) phase
// reduce; lanes 0..7 write the 64B fp32 out slice.
__global__ __launch_bounds__(256) void k_gather(
    const int* __restrict__ offs, const int* __restrict__ srcs,
    const __half* __restrict__ t2h, const float* __restrict__ dis,
    const float* __restrict__ bias, float* __restrict__ out, int N) {
  const int k = blockIdx.x & 7;             // column slice
  const int g = blockIdx.x >> 3;            // node group
  const int node = g * 4 + (threadIdx.x >> 6);
  if (node >= N) return;
  const int l = threadIdx.x & 63;
  const int ph = l >> 3;                    // edge phase 0..7
  const int c = l & 7;                      // half2 col within slice
  const int cb = k * 8 + c;                 // half2 col global
  const __half2* t2v = (const __half2*)t2h;

  const int s = offs[node], e = offs[node + 1];
  float2 acc;
  if (ph == 0) {  // self loop, counted once
    acc = __half22float2(t2v[(size_t)node * 64 + cb]);
  } else {
    acc = make_float2(0.f, 0.f);
  }
  int j = s + ph;
  for (; j + 8 < e; j += 16) {  // 2 edges per phase in flight
    int s0 = srcs[j], s1 = srcs[j + 8];     // pre-scaled src*64
    float2 f0 = __half22float2(t2v[(size_t)s0 + cb]);
    float2 f1 = __half22float2(t2v[(size_t)s1 + cb]);
    acc.x += f0.x + f1.x;
    acc.y += f0.y + f1.y;
  }
  if (j < e) {
    float2 f = __half22float2(t2v[(size_t)srcs[j] + cb]);
    acc.x += f.x;
    acc.y += f.y;
  }

  // reduce across the 8 phases (lane strides 8,16,32)
  acc.x += __shfl_xor(acc.x, 8);  acc.y += __shfl_xor(acc.y, 8);
  acc.x += __shfl_xor(acc.x, 16); acc.y += __shfl_xor(acc.y, 16);
  acc.x += __shfl_xor(acc.x, 32); acc.y += __shfl_xor(acc.y, 32);

  if (ph == 0) {
    const float dn = dis[node];
    const float2 b = *(const float2*)(bias + (size_t)cb * 2);
    float2 r = make_float2(dn * acc.x + b.x, dn * acc.y + b.y);
    *(float2*)(out + (size_t)node * 128 + (size_t)cb * 2) = r;
  }
}

extern "C" void kernel_launch(void* const* d_in, const int* in_sizes, int n_in,
                              void* d_out, int out_size, void* d_ws, size_t ws_size,
                              hipStream_t stream) {
  const float* x = (const float*)d_in[0];
  const int* ei = (const int*)d_in[1];   // int64 in reference, int32 on device: [2,E] flat
  const float* W = (const float*)d_in[2];
  const float* bias = (const float*)d_in[3];
  float* out = (float*)d_out;

  const int N = in_sizes[0] / 128;
  const int E = in_sizes[1] / 2;
  const int NBLK = cdiv(E, EPB);    // edge blocks (196)
  const int NBINS = cdiv(N, 256);   // coarse node buckets (196)
  const int M = 2 * NBINS * NBLK;   // concatenated hist length
  const int NB1 = cdiv(M, 1024);    // scan stage-1 blocks (<=256 required)

  // Workspace. Overlay region (hist|partials|ebA|ebB ~4.4MB) aliases t2h
  // (12.8MB): dead before k_gemm_mfma writes t2h. WhT outside overlay.
  __half* t2h = (__half*)d_ws;
  int* hist = (int*)d_ws;                      // [M]
  int* partials = hist + M;                    // [<=256] raw block sums
  int* ebA = partials + 256;                   // [E]  (src<<8)|(dst&255), dst-bucketed
  unsigned char* ebB = (unsigned char*)(ebA + E);  // [E] src&255, src-bucketed
  float* dis = (float*)(t2h + (size_t)N * 128);    // [N]
  int* offs = (int*)(dis + N);                 // [N+1]
  int* srcs = offs + (N + 1);                  // [E] pre-scaled src*64
  f16* WhT = (f16*)(srcs + E);                 // [128*128] fp16 B^T

  k_hist<<<NBLK, 256, 0, stream>>>(ei, E, hist, NBLK, NBINS, W, WhT);
  k_scan1<<<NB1, 256, 0, stream>>>(hist, partials, M);
  k_part<<<NBLK, 256, 0, stream>>>(ei, E, hist, partials, NB1, NBLK, NBINS, ebA, ebB);
  k_bucket<<<NBINS, 256, 0, stream>>>(ebA, ebB, hist, partials, NB1, NBLK, NBINS, E,
                                      dis, offs, srcs, N);
  k_gemm_mfma<<<cdiv(N, 64), 256, 0, stream>>>(x, WhT, dis, t2h, N);
  k_gather<<<cdiv(N, 4) * 8, 256, 0, stream>>>(offs, srcs, t2h, dis, bias, out, N);
}

// Round 13
// 171.010 us; speedup vs baseline: 1.1293x; 1.1293x over previous
//
#include <hip/hip_runtime.h>
#include <hip/hip_fp16.h>

// GCN layer on MI355X — CSR-gather, atomic-free CSR build, fp16 MFMA GEMM.
// out[c] = dis[c] * ( sum_{e: dst=c} t2[src_e] + t2[c] ) + bias
// t2[i] = dis[i] * (x @ W)[i], dis[i] = rsqrt(1 + outdeg(i)).
//
// Round-12 post-mortem: logical column-slicing of a monolithic [node][256B]
// row over-fetched 4x (32B strided reads pull 128B lines shared by 4 slices)
// -> 200MB FETCH, 131us. Fix: PHYSICAL slicing — 8 contiguous sub-tables
// t2s[k][node][16 f16] (1.6MB each). Gather blocks with k=blockIdx&7 land on
// XCD k (round-robin dispatch, same mapping as the guide's measured %8
// swizzle), so each L2 only ever misses on its own 1.6MB table and it stays
// resident. Per-edge read = 32B contiguous. Downside now bounded: if pinning
// fails, each L2 caches a mix totalling 12.8MB = r11's behavior (~40us).

#define EPB 4096  // edges per k_hist/k_part block

typedef _Float16 f16;
typedef f16 f16x8 __attribute__((ext_vector_type(8)));
typedef float f32x4 __attribute__((ext_vector_type(4)));

static inline int cdiv(int a, int b) { return (a + b - 1) / b; }

// P1: coarse histograms, transposed layout hist[bin*nblk + blk] (dst) and
// hist[HALF + bin*nblk + blk] (src), HALF = nbins*nblk.
// Blocks 0..63 also transpose W -> WhT fp16 (256 elems each, parallel).
__global__ __launch_bounds__(256) void k_hist(const int* __restrict__ ei, int E,
                                              int* __restrict__ hist, int nblk, int nbins,
                                              const float* __restrict__ W,
                                              f16* __restrict__ WhT) {
  __shared__ int ha[256], hb[256];
  const int tid = threadIdx.x, blk = blockIdx.x;
  ha[tid] = 0; hb[tid] = 0;
  __syncthreads();
  const int base = blk * EPB;
  const int lim = min(EPB, E - base);
  if ((E & 3) == 0) {
    for (int i = tid * 4; i + 3 < lim; i += 1024) {
      int4 s4 = *(const int4*)(ei + base + i);
      int4 d4 = *(const int4*)(ei + E + base + i);
      atomicAdd(&ha[d4.x >> 8], 1); atomicAdd(&hb[s4.x >> 8], 1);
      atomicAdd(&ha[d4.y >> 8], 1); atomicAdd(&hb[s4.y >> 8], 1);
      atomicAdd(&ha[d4.z >> 8], 1); atomicAdd(&hb[s4.z >> 8], 1);
      atomicAdd(&ha[d4.w >> 8], 1); atomicAdd(&hb[s4.w >> 8], 1);
    }
    for (int i = (lim & ~3) + tid; i < lim; i += 256) {
      atomicAdd(&ha[ei[E + base + i] >> 8], 1);
      atomicAdd(&hb[ei[base + i] >> 8], 1);
    }
  } else {
    for (int i = tid; i < lim; i += 256) {
      atomicAdd(&ha[ei[E + base + i] >> 8], 1);
      atomicAdd(&hb[ei[base + i] >> 8], 1);
    }
  }
  if (blk < 64) {  // W[k][c] -> WhT[c][k], 64 blocks x 256 = 16384 elems
    int i = blk * 256 + tid;
    int k = i >> 7, c = i & 127;
    WhT[c * 128 + k] = (f16)W[i];
  }
  __syncthreads();
  if (tid < nbins) {
    hist[tid * nblk + blk] = ha[tid];
    hist[nbins * nblk + tid * nblk + blk] = hb[tid];
  }
}

// Hierarchical exclusive scan stage 1 (in place), 1024 elems/block.
// partials keeps RAW block sums; consumers scan them in LDS themselves.
__global__ __launch_bounds__(256) void k_scan1(int* __restrict__ a,
                                               int* __restrict__ partials, int M) {
  __shared__ int ws[256];
  const int tid = threadIdx.x;
  const int i0 = blockIdx.x * 1024 + tid * 4;
  int v0 = (i0 + 0 < M) ? a[i0 + 0] : 0;
  int v1 = (i0 + 1 < M) ? a[i0 + 1] : 0;
  int v2 = (i0 + 2 < M) ? a[i0 + 2] : 0;
  int v3 = (i0 + 3 < M) ? a[i0 + 3] : 0;
  int tsum = v0 + v1 + v2 + v3;
  ws[tid] = tsum;
  __syncthreads();
#pragma unroll
  for (int off = 1; off < 256; off <<= 1) {
    int add = (tid >= off) ? ws[tid - off] : 0;
    __syncthreads();
    ws[tid] += add;
    __syncthreads();
  }
  int texcl = ws[tid] - tsum;
  if (tid == 255) partials[blockIdx.x] = ws[255];
  if (i0 + 0 < M) a[i0 + 0] = texcl;
  if (i0 + 1 < M) a[i0 + 1] = texcl + v0;
  if (i0 + 2 < M) a[i0 + 2] = texcl + v0 + v1;
  if (i0 + 3 < M) a[i0 + 3] = texcl + v0 + v1 + v2;
}

// Shared helper: exclusive-scan nb1 (<=256) raw partials into shP.
__device__ __forceinline__ void scan_partials(const int* __restrict__ partials,
                                              int nb1, int* shP, int tid) {
  int v = (tid < nb1) ? partials[tid] : 0;
  shP[tid] = v;
  __syncthreads();
#pragma unroll
  for (int off = 1; off < 256; off <<= 1) {
    int add = (tid >= off) ? shP[tid - off] : 0;
    __syncthreads();
    shP[tid] += add;
    __syncthreads();
  }
  int excl = shP[tid] - v;
  __syncthreads();
  shP[tid] = excl;
  __syncthreads();
}

// P2: partition edges into coarse buckets. ebA[posA] = (src<<8)|(dst&255)
// (dst-bucketed), ebB[posB] = src&255 (src-bucketed, uchar). Plain stores only.
__global__ __launch_bounds__(256) void k_part(const int* __restrict__ ei, int E,
                                              const int* __restrict__ hist,
                                              const int* __restrict__ partials, int nb1,
                                              int nblk, int nbins,
                                              int* __restrict__ ebA,
                                              unsigned char* __restrict__ ebB) {
  __shared__ int cA[256], cB[256], shP[256];
  const int tid = threadIdx.x, blk = blockIdx.x;
  const int HALF = nbins * nblk;
  scan_partials(partials, nb1, shP, tid);
  if (tid < nbins) {
    int ia = tid * nblk + blk;
    int ib = HALF + tid * nblk + blk;
    cA[tid] = hist[ia] + shP[ia >> 10];
    cB[tid] = hist[ib] + shP[ib >> 10] - E;
  }
  __syncthreads();
  const int base = blk * EPB;
  const int lim = min(EPB, E - base);
  if ((E & 3) == 0) {
    for (int i = tid * 4; i + 3 < lim; i += 1024) {
      int4 s4 = *(const int4*)(ei + base + i);
      int4 d4 = *(const int4*)(ei + E + base + i);
      int pa, pb;
      pa = atomicAdd(&cA[d4.x >> 8], 1); ebA[pa] = (s4.x << 8) | (d4.x & 255);
      pb = atomicAdd(&cB[s4.x >> 8], 1); ebB[pb] = (unsigned char)(s4.x & 255);
      pa = atomicAdd(&cA[d4.y >> 8], 1); ebA[pa] = (s4.y << 8) | (d4.y & 255);
      pb = atomicAdd(&cB[s4.y >> 8], 1); ebB[pb] = (unsigned char)(s4.y & 255);
      pa = atomicAdd(&cA[d4.z >> 8], 1); ebA[pa] = (s4.z << 8) | (d4.z & 255);
      pb = atomicAdd(&cB[s4.z >> 8], 1); ebB[pb] = (unsigned char)(s4.z & 255);
      pa = atomicAdd(&cA[d4.w >> 8], 1); ebA[pa] = (s4.w << 8) | (d4.w & 255);
      pb = atomicAdd(&cB[s4.w >> 8], 1); ebB[pb] = (unsigned char)(s4.w & 255);
    }
    for (int i = (lim & ~3) + tid; i < lim; i += 256) {
      int s = ei[base + i], d = ei[E + base + i];
      int pa = atomicAdd(&cA[d >> 8], 1); ebA[pa] = (s << 8) | (d & 255);
      int pb = atomicAdd(&cB[s >> 8], 1); ebB[pb] = (unsigned char)(s & 255);
    }
  } else {
    for (int i = tid; i < lim; i += 256) {
      int s = ei[base + i], d = ei[E + base + i];
      int pa = atomicAdd(&cA[d >> 8], 1); ebA[pa] = (s << 8) | (d & 255);
      int pb = atomicAdd(&cB[s >> 8], 1); ebB[pb] = (unsigned char)(s & 255);
    }
  }
}

// P3 merged: per coarse bucket b,
//  phase 1 (deg): fine count of src over ebB bucket -> dis = rsqrt(1+cnt)
//  phase 2 (csr): fine count+scan of dst over ebA bucket -> offs, place srcs
// srcs stored PRE-SCALED by 8 (half2-row units within a slice table).
__global__ __launch_bounds__(256) void k_bucket(
    const int* __restrict__ ebA, const unsigned char* __restrict__ ebB,
    const int* __restrict__ hist, const int* __restrict__ partials, int nb1,
    int nblk, int nbins, int E,
    float* __restrict__ dis, int* __restrict__ offs,
    int* __restrict__ srcs, int N) {
  __shared__ int h[256], tmp[256], cur[256], shP[256];
  const int tid = threadIdx.x, b = blockIdx.x;
  const int HALF = nbins * nblk;
  const int node = b * 256 + tid;
  scan_partials(partials, nb1, shP, tid);

  // --- phase 1: out-degree -> dis ---
  {
    int i0 = HALF + b * nblk;
    const int bs = hist[i0] + shP[i0 >> 10] - E;
    int be = E;
    if (b + 1 < nbins) {
      int i1 = HALF + (b + 1) * nblk;
      be = hist[i1] + shP[i1 >> 10] - E;
    }
    h[tid] = 0;
    __syncthreads();
    for (int j = bs + tid; j < be; j += 256) atomicAdd(&h[ebB[j]], 1);
    __syncthreads();
    if (node < N) dis[node] = rsqrtf(1.0f + (float)h[tid]);
    __syncthreads();
  }

  // --- phase 2: CSR offs + srcs ---
  {
    int i0 = b * nblk;
    const int bs = hist[i0] + shP[i0 >> 10];
    int be = E;
    if (b + 1 < nbins) {
      int i1 = (b + 1) * nblk;
      be = hist[i1] + shP[i1 >> 10];
    }
    h[tid] = 0;
    __syncthreads();
    for (int j = bs + tid; j < be; j += 256) atomicAdd(&h[ebA[j] & 255], 1);
    __syncthreads();
    int cnt = h[tid];
    tmp[tid] = cnt;
    __syncthreads();
#pragma unroll
    for (int off = 1; off < 256; off <<= 1) {
      int add = (tid >= off) ? tmp[tid - off] : 0;
      __syncthreads();
      tmp[tid] += add;
      __syncthreads();
    }
    int gpos = bs + tmp[tid] - cnt;
    if (node < N) offs[node] = gpos;
    cur[tid] = gpos;
    __syncthreads();
    for (int j = bs + tid; j < be; j += 256) {
      int v = ebA[j];
      int p = atomicAdd(&cur[v & 255], 1);
      srcs[p] = (v >> 8) << 3;  // pre-scaled: src * 8 half2-units (slice row)
    }
    if (b == 0 && tid == 0) offs[N] = E;
  }
}

// MFMA GEMM: t2 = fp16( dis[r] * sum_k x[r][k] * W[k][c] ), written to the
// SLICED layout t2s[k][r][16 f16], slice k = cols [k*16,(k+1)*16).
// 256 thr = 4 waves; wave w owns rows [blk*64 + w*16, +16), all 128 cols.
// C/D layout: col = lane&15, row = (lane>>4)*4 + reg  [guide §3, m89].
__global__ __launch_bounds__(256) void k_gemm_mfma(
    const float* __restrict__ x, const f16* __restrict__ WhT,
    const float* __restrict__ dis, f16* __restrict__ t2s, int N) {
  __shared__ __align__(16) f16 cs[4][16][136];  // stride 272B = 17x16B
  const int tid = threadIdx.x;
  const int w = tid >> 6, l = tid & 63;
  const int l15 = l & 15, lg = l >> 4;
  const int wr0 = blockIdx.x * 64 + w * 16;
  const int arow = wr0 + l15;
  const bool avalid = arow < N;

  f32x4 acc[8];
#pragma unroll
  for (int ct = 0; ct < 8; ++ct) acc[ct] = (f32x4){0.f, 0.f, 0.f, 0.f};

#pragma unroll
  for (int kc = 0; kc < 4; ++kc) {
    f16x8 af;
    if (avalid) {
      const float4* ap = (const float4*)(x + (size_t)arow * 128 + kc * 32 + lg * 8);
      float4 a0 = ap[0], a1 = ap[1];
      af[0] = (f16)a0.x; af[1] = (f16)a0.y; af[2] = (f16)a0.z; af[3] = (f16)a0.w;
      af[4] = (f16)a1.x; af[5] = (f16)a1.y; af[6] = (f16)a1.z; af[7] = (f16)a1.w;
    } else {
#pragma unroll
      for (int j = 0; j < 8; ++j) af[j] = (f16)0.f;
    }
#pragma unroll
    for (int ct = 0; ct < 8; ++ct) {
      f16x8 bf = *(const f16x8*)(WhT + (ct * 16 + l15) * 128 + kc * 32 + lg * 8);
      acc[ct] = __builtin_amdgcn_mfma_f32_16x16x32_f16(af, bf, acc[ct], 0, 0, 0);
    }
  }

  // scale rows by dis and stash (transposed per-wave) in LDS
  float d4[4];
#pragma unroll
  for (int j = 0; j < 4; ++j) {
    int r = wr0 + lg * 4 + j;
    d4[j] = (r < N) ? dis[r] : 0.f;
  }
#pragma unroll
  for (int ct = 0; ct < 8; ++ct)
#pragma unroll
    for (int j = 0; j < 4; ++j)
      cs[w][lg * 4 + j][ct * 16 + l15] = (f16)(d4[j] * acc[ct][j]);
  __syncthreads();

  // write-out to sliced layout: seg -> slice k=seg>>1, half h=seg&1.
  // 16B stores; even/odd seg pairs form 32B contiguous runs per slice row.
#pragma unroll
  for (int it = 0; it < 4; ++it) {
    int t = it * 64 + l;
    int row = t >> 4, seg = t & 15;
    int gr = wr0 + row;
    if (gr < N) {
      int k = seg >> 1, h = seg & 1;
      *(f16x8*)(t2s + ((size_t)k * N + gr) * 16 + h * 8) = *(const f16x8*)&cs[w][row][seg * 8];
    }
  }
}

// XCD-pinned sliced gather. Grid = (node-group g) x (slice k = blockIdx&7);
// round-robin dispatch pins slice k to XCD k, whose L2 caches only its own
// 1.6MB table t2s[k]. Wave = one node; lane l -> (phase ph=l>>3 over edges,
// half2 col c=l&7). Per edge: 8 lanes x 4B = 32B contiguous within slice.
// shfl_xor(8/16/32) phase reduce; ph==0 lanes write the 64B fp32 out slice.
__global__ __launch_bounds__(256) void k_gather(
    const int* __restrict__ offs, const int* __restrict__ srcs,
    const f16* __restrict__ t2s, const float* __restrict__ dis,
    const float* __restrict__ bias, float* __restrict__ out, int N) {
  const int k = blockIdx.x & 7;             // column slice / XCD
  const int g = blockIdx.x >> 3;            // node group
  const int node = g * 4 + (threadIdx.x >> 6);
  if (node >= N) return;
  const int l = threadIdx.x & 63;
  const int ph = l >> 3;                    // edge phase 0..7
  const int c = l & 7;                      // half2 col within slice
  const __half2* sv = (const __half2*)(t2s + (size_t)k * N * 16);  // slice base

  const int s = offs[node], e = offs[node + 1];
  float2 acc;
  if (ph == 0) {  // self loop, counted once
    acc = __half22float2(sv[(size_t)node * 8 + c]);
  } else {
    acc = make_float2(0.f, 0.f);
  }
  int j = s + ph;
  for (; j + 8 < e; j += 16) {  // 2 edges per phase in flight
    int s0 = srcs[j], s1 = srcs[j + 8];     // pre-scaled src*8
    float2 f0 = __half22float2(sv[(size_t)s0 + c]);
    float2 f1 = __half22float2(sv[(size_t)s1 + c]);
    acc.x += f0.x + f1.x;
    acc.y += f0.y + f1.y;
  }
  if (j < e) {
    float2 f = __half22float2(sv[(size_t)srcs[j] + c]);
    acc.x += f.x;
    acc.y += f.y;
  }

  // reduce across the 8 phases (lane strides 8,16,32)
  acc.x += __shfl_xor(acc.x, 8);  acc.y += __shfl_xor(acc.y, 8);
  acc.x += __shfl_xor(acc.x, 16); acc.y += __shfl_xor(acc.y, 16);
  acc.x += __shfl_xor(acc.x, 32); acc.y += __shfl_xor(acc.y, 32);

  if (ph == 0) {
    const float dn = dis[node];
    const float2 b = *(const float2*)(bias + (size_t)(k * 8 + c) * 2);
    float2 r = make_float2(dn * acc.x + b.x, dn * acc.y + b.y);
    *(float2*)(out + (size_t)node * 128 + (size_t)(k * 8 + c) * 2) = r;
  }
}

extern "C" void kernel_launch(void* const* d_in, const int* in_sizes, int n_in,
                              void* d_out, int out_size, void* d_ws, size_t ws_size,
                              hipStream_t stream) {
  const float* x = (const float*)d_in[0];
  const int* ei = (const int*)d_in[1];   // int64 in reference, int32 on device: [2,E] flat
  const float* W = (const float*)d_in[2];
  const float* bias = (const float*)d_in[3];
  float* out = (float*)d_out;

  const int N = in_sizes[0] / 128;
  const int E = in_sizes[1] / 2;
  const int NBLK = cdiv(E, EPB);    // edge blocks (196)
  const int NBINS = cdiv(N, 256);   // coarse node buckets (196)
  const int M = 2 * NBINS * NBLK;   // concatenated hist length
  const int NB1 = cdiv(M, 1024);    // scan stage-1 blocks (<=256 required)

  // Workspace. Overlay region (hist|partials|ebA|ebB ~4.4MB) aliases t2s
  // (12.8MB): dead before k_gemm_mfma writes t2s. WhT outside overlay.
  f16* t2s = (f16*)d_ws;                       // 8 x [N][16] f16 slice tables
  int* hist = (int*)d_ws;                      // [M]
  int* partials = hist + M;                    // [<=256] raw block sums
  int* ebA = partials + 256;                   // [E]  (src<<8)|(dst&255), dst-bucketed
  unsigned char* ebB = (unsigned char*)(ebA + E);  // [E] src&255, src-bucketed
  float* dis = (float*)(t2s + (size_t)N * 128);    // [N]
  int* offs = (int*)(dis + N);                 // [N+1]
  int* srcs = offs + (N + 1);                  // [E] pre-scaled src*8
  f16* WhT = (f16*)(srcs + E);                 // [128*128] fp16 B^T

  k_hist<<<NBLK, 256, 0, stream>>>(ei, E, hist, NBLK, NBINS, W, WhT);
  k_scan1<<<NB1, 256, 0, stream>>>(hist, partials, M);
  k_part<<<NBLK, 256, 0, stream>>>(ei, E, hist, partials, NB1, NBLK, NBINS, ebA, ebB);
  k_bucket<<<NBINS, 256, 0, stream>>>(ebA, ebB, hist, partials, NB1, NBLK, NBINS, E,
                                      dis, offs, srcs, N);
  k_gemm_mfma<<<cdiv(N, 64), 256, 0, stream>>>(x, WhT, dis, t2s, N);
  k_gather<<<cdiv(N, 4) * 8, 256, 0, stream>>>(offs, srcs, t2s, dis, bias, out, N);
}

// Round 14
// 102.244 us; speedup vs baseline: 1.8888x; 1.6726x over previous
//
#include <hip/hip_runtime.h>
#include <hip/hip_fp16.h>

// GCN layer on MI355X — CSR-gather, atomic-free CSR build, fp16 MFMA GEMM.
// out[c] = dis[c] * ( sum_{e: dst=c} t2[src_e] + t2[c] ) + bias
// t2[i] = dis[i] * (x @ W)[i], dis[i] = rsqrt(1 + outdeg(i)).
//
// Round-13 post-mortem: physical slicing DID fix traffic (FETCH 93->20MB)
// but the phase-split wave structure cost 2.7x in VALU/latency overhead
// (109us, VALUBusy 46%). Lesson: keep the instruction-minimal gather (one
// 256B row-read per edge, wave=node); attack latency with MORE INDEPENDENT
// CHAINS instead. This round = exact r11 revert + gather handles 2 nodes
// per wave (interleaved A/B edge chains, 8 loads in flight, no shuffles).

#define EPB 4096  // edges per k_hist/k_part block

typedef _Float16 f16;
typedef f16 f16x8 __attribute__((ext_vector_type(8)));
typedef float f32x4 __attribute__((ext_vector_type(4)));

static inline int cdiv(int a, int b) { return (a + b - 1) / b; }

// P1: coarse histograms, transposed layout hist[bin*nblk + blk] (dst) and
// hist[HALF + bin*nblk + blk] (src), HALF = nbins*nblk.
// Blocks 0..63 also transpose W -> WhT fp16 (256 elems each, parallel).
__global__ __launch_bounds__(256) void k_hist(const int* __restrict__ ei, int E,
                                              int* __restrict__ hist, int nblk, int nbins,
                                              const float* __restrict__ W,
                                              f16* __restrict__ WhT) {
  __shared__ int ha[256], hb[256];
  const int tid = threadIdx.x, blk = blockIdx.x;
  ha[tid] = 0; hb[tid] = 0;
  __syncthreads();
  const int base = blk * EPB;
  const int lim = min(EPB, E - base);
  if ((E & 3) == 0) {
    for (int i = tid * 4; i + 3 < lim; i += 1024) {
      int4 s4 = *(const int4*)(ei + base + i);
      int4 d4 = *(const int4*)(ei + E + base + i);
      atomicAdd(&ha[d4.x >> 8], 1); atomicAdd(&hb[s4.x >> 8], 1);
      atomicAdd(&ha[d4.y >> 8], 1); atomicAdd(&hb[s4.y >> 8], 1);
      atomicAdd(&ha[d4.z >> 8], 1); atomicAdd(&hb[s4.z >> 8], 1);
      atomicAdd(&ha[d4.w >> 8], 1); atomicAdd(&hb[s4.w >> 8], 1);
    }
    for (int i = (lim & ~3) + tid; i < lim; i += 256) {
      atomicAdd(&ha[ei[E + base + i] >> 8], 1);
      atomicAdd(&hb[ei[base + i] >> 8], 1);
    }
  } else {
    for (int i = tid; i < lim; i += 256) {
      atomicAdd(&ha[ei[E + base + i] >> 8], 1);
      atomicAdd(&hb[ei[base + i] >> 8], 1);
    }
  }
  if (blk < 64) {  // W[k][c] -> WhT[c][k], 64 blocks x 256 = 16384 elems
    int i = blk * 256 + tid;
    int k = i >> 7, c = i & 127;
    WhT[c * 128 + k] = (f16)W[i];
  }
  __syncthreads();
  if (tid < nbins) {
    hist[tid * nblk + blk] = ha[tid];
    hist[nbins * nblk + tid * nblk + blk] = hb[tid];
  }
}

// Hierarchical exclusive scan stage 1 (in place), 1024 elems/block.
// partials keeps RAW block sums; consumers scan them in LDS themselves.
__global__ __launch_bounds__(256) void k_scan1(int* __restrict__ a,
                                               int* __restrict__ partials, int M) {
  __shared__ int ws[256];
  const int tid = threadIdx.x;
  const int i0 = blockIdx.x * 1024 + tid * 4;
  int v0 = (i0 + 0 < M) ? a[i0 + 0] : 0;
  int v1 = (i0 + 1 < M) ? a[i0 + 1] : 0;
  int v2 = (i0 + 2 < M) ? a[i0 + 2] : 0;
  int v3 = (i0 + 3 < M) ? a[i0 + 3] : 0;
  int tsum = v0 + v1 + v2 + v3;
  ws[tid] = tsum;
  __syncthreads();
#pragma unroll
  for (int off = 1; off < 256; off <<= 1) {
    int add = (tid >= off) ? ws[tid - off] : 0;
    __syncthreads();
    ws[tid] += add;
    __syncthreads();
  }
  int texcl = ws[tid] - tsum;
  if (tid == 255) partials[blockIdx.x] = ws[255];
  if (i0 + 0 < M) a[i0 + 0] = texcl;
  if (i0 + 1 < M) a[i0 + 1] = texcl + v0;
  if (i0 + 2 < M) a[i0 + 2] = texcl + v0 + v1;
  if (i0 + 3 < M) a[i0 + 3] = texcl + v0 + v1 + v2;
}

// Shared helper: exclusive-scan nb1 (<=256) raw partials into shP.
__device__ __forceinline__ void scan_partials(const int* __restrict__ partials,
                                              int nb1, int* shP, int tid) {
  int v = (tid < nb1) ? partials[tid] : 0;
  shP[tid] = v;
  __syncthreads();
#pragma unroll
  for (int off = 1; off < 256; off <<= 1) {
    int add = (tid >= off) ? shP[tid - off] : 0;
    __syncthreads();
    shP[tid] += add;
    __syncthreads();
  }
  int excl = shP[tid] - v;
  __syncthreads();
  shP[tid] = excl;
  __syncthreads();
}

// P2: partition edges into coarse buckets. ebA[posA] = (src<<8)|(dst&255)
// (dst-bucketed), ebB[posB] = src&255 (src-bucketed, uchar). Plain stores only.
__global__ __launch_bounds__(256) void k_part(const int* __restrict__ ei, int E,
                                              const int* __restrict__ hist,
                                              const int* __restrict__ partials, int nb1,
                                              int nblk, int nbins,
                                              int* __restrict__ ebA,
                                              unsigned char* __restrict__ ebB) {
  __shared__ int cA[256], cB[256], shP[256];
  const int tid = threadIdx.x, blk = blockIdx.x;
  const int HALF = nbins * nblk;
  scan_partials(partials, nb1, shP, tid);
  if (tid < nbins) {
    int ia = tid * nblk + blk;
    int ib = HALF + tid * nblk + blk;
    cA[tid] = hist[ia] + shP[ia >> 10];
    cB[tid] = hist[ib] + shP[ib >> 10] - E;
  }
  __syncthreads();
  const int base = blk * EPB;
  const int lim = min(EPB, E - base);
  if ((E & 3) == 0) {
    for (int i = tid * 4; i + 3 < lim; i += 1024) {
      int4 s4 = *(const int4*)(ei + base + i);
      int4 d4 = *(const int4*)(ei + E + base + i);
      int pa, pb;
      pa = atomicAdd(&cA[d4.x >> 8], 1); ebA[pa] = (s4.x << 8) | (d4.x & 255);
      pb = atomicAdd(&cB[s4.x >> 8], 1); ebB[pb] = (unsigned char)(s4.x & 255);
      pa = atomicAdd(&cA[d4.y >> 8], 1); ebA[pa] = (s4.y << 8) | (d4.y & 255);
      pb = atomicAdd(&cB[s4.y >> 8], 1); ebB[pb] = (unsigned char)(s4.y & 255);
      pa = atomicAdd(&cA[d4.z >> 8], 1); ebA[pa] = (s4.z << 8) | (d4.z & 255);
      pb = atomicAdd(&cB[s4.z >> 8], 1); ebB[pb] = (unsigned char)(s4.z & 255);
      pa = atomicAdd(&cA[d4.w >> 8], 1); ebA[pa] = (s4.w << 8) | (d4.w & 255);
      pb = atomicAdd(&cB[s4.w >> 8], 1); ebB[pb] = (unsigned char)(s4.w & 255);
    }
    for (int i = (lim & ~3) + tid; i < lim; i += 256) {
      int s = ei[base + i], d = ei[E + base + i];
      int pa = atomicAdd(&cA[d >> 8], 1); ebA[pa] = (s << 8) | (d & 255);
      int pb = atomicAdd(&cB[s >> 8], 1); ebB[pb] = (unsigned char)(s & 255);
    }
  } else {
    for (int i = tid; i < lim; i += 256) {
      int s = ei[base + i], d = ei[E + base + i];
      int pa = atomicAdd(&cA[d >> 8], 1); ebA[pa] = (s << 8) | (d & 255);
      int pb = atomicAdd(&cB[s >> 8], 1); ebB[pb] = (unsigned char)(s & 255);
    }
  }
}

// P3 merged: per coarse bucket b,
//  phase 1 (deg): fine count of src over ebB bucket -> dis = rsqrt(1+cnt)
//  phase 2 (csr): fine count+scan of dst over ebA bucket -> offs, place srcs
// srcs stored PRE-SCALED by 64 (half2-row units) for the gather.
__global__ __launch_bounds__(256) void k_bucket(
    const int* __restrict__ ebA, const unsigned char* __restrict__ ebB,
    const int* __restrict__ hist, const int* __restrict__ partials, int nb1,
    int nblk, int nbins, int E,
    float* __restrict__ dis, int* __restrict__ offs,
    int* __restrict__ srcs, int N) {
  __shared__ int h[256], tmp[256], cur[256], shP[256];
  const int tid = threadIdx.x, b = blockIdx.x;
  const int HALF = nbins * nblk;
  const int node = b * 256 + tid;
  scan_partials(partials, nb1, shP, tid);

  // --- phase 1: out-degree -> dis ---
  {
    int i0 = HALF + b * nblk;
    const int bs = hist[i0] + shP[i0 >> 10] - E;
    int be = E;
    if (b + 1 < nbins) {
      int i1 = HALF + (b + 1) * nblk;
      be = hist[i1] + shP[i1 >> 10] - E;
    }
    h[tid] = 0;
    __syncthreads();
    for (int j = bs + tid; j < be; j += 256) atomicAdd(&h[ebB[j]], 1);
    __syncthreads();
    if (node < N) dis[node] = rsqrtf(1.0f + (float)h[tid]);
    __syncthreads();
  }

  // --- phase 2: CSR offs + srcs ---
  {
    int i0 = b * nblk;
    const int bs = hist[i0] + shP[i0 >> 10];
    int be = E;
    if (b + 1 < nbins) {
      int i1 = (b + 1) * nblk;
      be = hist[i1] + shP[i1 >> 10];
    }
    h[tid] = 0;
    __syncthreads();
    for (int j = bs + tid; j < be; j += 256) atomicAdd(&h[ebA[j] & 255], 1);
    __syncthreads();
    int cnt = h[tid];
    tmp[tid] = cnt;
    __syncthreads();
#pragma unroll
    for (int off = 1; off < 256; off <<= 1) {
      int add = (tid >= off) ? tmp[tid - off] : 0;
      __syncthreads();
      tmp[tid] += add;
      __syncthreads();
    }
    int gpos = bs + tmp[tid] - cnt;
    if (node < N) offs[node] = gpos;
    cur[tid] = gpos;
    __syncthreads();
    for (int j = bs + tid; j < be; j += 256) {
      int v = ebA[j];
      int p = atomicAdd(&cur[v & 255], 1);
      srcs[p] = (v >> 8) << 6;  // pre-scaled: src * 64 half2-units
    }
    if (b == 0 && tid == 0) offs[N] = E;
  }
}

// MFMA GEMM: t2h[r][c] = fp16( dis[r] * sum_k x[r][k] * W[k][c] ).
// 256 thr = 4 waves; wave w owns rows [blk*64 + w*16, +16), all 128 cols.
// Per wave: 8 col-tiles x 4 k-chunks of mfma_f32_16x16x32_f16.
// C/D layout: col = lane&15, row = (lane>>4)*4 + reg  [guide §3, m89].
__global__ __launch_bounds__(256) void k_gemm_mfma(
    const float* __restrict__ x, const f16* __restrict__ WhT,
    const float* __restrict__ dis, __half* __restrict__ t2h, int N) {
  __shared__ __align__(16) f16 cs[4][16][136];  // stride 272B = 17x16B
  const int tid = threadIdx.x;
  const int w = tid >> 6, l = tid & 63;
  const int l15 = l & 15, lg = l >> 4;
  const int wr0 = blockIdx.x * 64 + w * 16;
  const int arow = wr0 + l15;
  const bool avalid = arow < N;

  f32x4 acc[8];
#pragma unroll
  for (int ct = 0; ct < 8; ++ct) acc[ct] = (f32x4){0.f, 0.f, 0.f, 0.f};

#pragma unroll
  for (int kc = 0; kc < 4; ++kc) {
    f16x8 af;
    if (avalid) {
      const float4* ap = (const float4*)(x + (size_t)arow * 128 + kc * 32 + lg * 8);
      float4 a0 = ap[0], a1 = ap[1];
      af[0] = (f16)a0.x; af[1] = (f16)a0.y; af[2] = (f16)a0.z; af[3] = (f16)a0.w;
      af[4] = (f16)a1.x; af[5] = (f16)a1.y; af[6] = (f16)a1.z; af[7] = (f16)a1.w;
    } else {
#pragma unroll
      for (int j = 0; j < 8; ++j) af[j] = (f16)0.f;
    }
#pragma unroll
    for (int ct = 0; ct < 8; ++ct) {
      f16x8 bf = *(const f16x8*)(WhT + (ct * 16 + l15) * 128 + kc * 32 + lg * 8);
      acc[ct] = __builtin_amdgcn_mfma_f32_16x16x32_f16(af, bf, acc[ct], 0, 0, 0);
    }
  }

  // scale rows by dis and stash (transposed per-wave) in LDS
  float d4[4];
#pragma unroll
  for (int j = 0; j < 4; ++j) {
    int r = wr0 + lg * 4 + j;
    d4[j] = (r < N) ? dis[r] : 0.f;
  }
#pragma unroll
  for (int ct = 0; ct < 8; ++ct)
#pragma unroll
    for (int j = 0; j < 4; ++j)
      cs[w][lg * 4 + j][ct * 16 + l15] = (f16)(d4[j] * acc[ct][j]);
  __syncthreads();

  // coalesced write-out: 4 iters x 64 lanes x 16B
#pragma unroll
  for (int it = 0; it < 4; ++it) {
    int t = it * 64 + l;
    int row = t >> 4, seg = t & 15;
    int gr = wr0 + row;
    if (gr < N)
      *(f16x8*)((f16*)t2h + (size_t)gr * 128 + seg * 8) = *(const f16x8*)&cs[w][row][seg * 8];
  }
}

// One 64-lane wave per TWO nodes (A,B); lane owns __half2 col = lane*2 of
// each 256B row. A/B edge chains interleaved: 8 independent row-loads in
// flight; instruction payload stays 256B/row-load; no shuffles.
// srcs entries are pre-scaled (src*64) half2-row offsets.
__global__ __launch_bounds__(256) void k_gather(
    const int* __restrict__ offs, const int* __restrict__ srcs,
    const __half* __restrict__ t2h, const float* __restrict__ dis,
    const float* __restrict__ bias, float* __restrict__ out, int N) {
  const int w = threadIdx.x >> 6;
  const int lane = threadIdx.x & 63;
  const int nA = blockIdx.x * 8 + w * 2;
  const int nB = nA + 1;
  if (nA >= N) return;
  const bool hasB = nB < N;
  const __half2* t2v = (const __half2*)t2h;

  const int sA = offs[nA], eA = offs[nA + 1];
  int sB = 0, eB = 0;
  float2 accA = __half22float2(t2v[(size_t)nA * 64 + lane]);  // self loop A
  float2 accB = make_float2(0.f, 0.f);
  if (hasB) {
    sB = offs[nB + 0]; eB = offs[nB + 1];
    accB = __half22float2(t2v[(size_t)nB * 64 + lane]);       // self loop B
  }

  int ja = sA, jb = sB;
  // joint loop: 4 loads per chain, 8 in flight
  while (ja + 3 < eA && jb + 3 < eB) {
    int a0 = srcs[ja], a1 = srcs[ja + 1], a2 = srcs[ja + 2], a3 = srcs[ja + 3];
    int b0 = srcs[jb], b1 = srcs[jb + 1], b2 = srcs[jb + 2], b3 = srcs[jb + 3];
    float2 va0 = __half22float2(t2v[(size_t)a0 + lane]);
    float2 va1 = __half22float2(t2v[(size_t)a1 + lane]);
    float2 va2 = __half22float2(t2v[(size_t)a2 + lane]);
    float2 va3 = __half22float2(t2v[(size_t)a3 + lane]);
    float2 vb0 = __half22float2(t2v[(size_t)b0 + lane]);
    float2 vb1 = __half22float2(t2v[(size_t)b1 + lane]);
    float2 vb2 = __half22float2(t2v[(size_t)b2 + lane]);
    float2 vb3 = __half22float2(t2v[(size_t)b3 + lane]);
    accA.x += (va0.x + va1.x) + (va2.x + va3.x);
    accA.y += (va0.y + va1.y) + (va2.y + va3.y);
    accB.x += (vb0.x + vb1.x) + (vb2.x + vb3.x);
    accB.y += (vb0.y + vb1.y) + (vb2.y + vb3.y);
    ja += 4; jb += 4;
  }
  // drain A
  for (; ja + 3 < eA; ja += 4) {
    int a0 = srcs[ja], a1 = srcs[ja + 1], a2 = srcs[ja + 2], a3 = srcs[ja + 3];
    float2 v0 = __half22float2(t2v[(size_t)a0 + lane]);
    float2 v1 = __half22float2(t2v[(size_t)a1 + lane]);
    float2 v2 = __half22float2(t2v[(size_t)a2 + lane]);
    float2 v3 = __half22float2(t2v[(size_t)a3 + lane]);
    accA.x += (v0.x + v1.x) + (v2.x + v3.x);
    accA.y += (v0.y + v1.y) + (v2.y + v3.y);
  }
  for (; ja < eA; ++ja) {
    float2 v = __half22float2(t2v[(size_t)srcs[ja] + lane]);
    accA.x += v.x; accA.y += v.y;
  }
  // drain B
  for (; jb + 3 < eB; jb += 4) {
    int b0 = srcs[jb], b1 = srcs[jb + 1], b2 = srcs[jb + 2], b3 = srcs[jb + 3];
    float2 v0 = __half22float2(t2v[(size_t)b0 + lane]);
    float2 v1 = __half22float2(t2v[(size_t)b1 + lane]);
    float2 v2 = __half22float2(t2v[(size_t)b2 + lane]);
    float2 v3 = __half22float2(t2v[(size_t)b3 + lane]);
    accB.x += (v0.x + v1.x) + (v2.x + v3.x);
    accB.y += (v0.y + v1.y) + (v2.y + v3.y);
  }
  for (; jb < eB; ++jb) {
    float2 v = __half22float2(t2v[(size_t)srcs[jb] + lane]);
    accB.x += v.x; accB.y += v.y;
  }

  const float2 b = *(const float2*)(bias + (size_t)lane * 2);
  {
    const float dn = dis[nA];
    float2 r = make_float2(dn * accA.x + b.x, dn * accA.y + b.y);
    *(float2*)(out + (size_t)nA * 128 + (size_t)lane * 2) = r;
  }
  if (hasB) {
    const float dn = dis[nB];
    float2 r = make_float2(dn * accB.x + b.x, dn * accB.y + b.y);
    *(float2*)(out + (size_t)nB * 128 + (size_t)lane * 2) = r;
  }
}

extern "C" void kernel_launch(void* const* d_in, const int* in_sizes, int n_in,
                              void* d_out, int out_size, void* d_ws, size_t ws_size,
                              hipStream_t stream) {
  const float* x = (const float*)d_in[0];
  const int* ei = (const int*)d_in[1];   // int64 in reference, int32 on device: [2,E] flat
  const float* W = (const float*)d_in[2];
  const float* bias = (const float*)d_in[3];
  float* out = (float*)d_out;

  const int N = in_sizes[0] / 128;
  const int E = in_sizes[1] / 2;
  const int NBLK = cdiv(E, EPB);    // edge blocks (196)
  const int NBINS = cdiv(N, 256);   // coarse node buckets (196)
  const int M = 2 * NBINS * NBLK;   // concatenated hist length
  const int NB1 = cdiv(M, 1024);    // scan stage-1 blocks (<=256 required)

  // Workspace. Overlay region (hist|partials|ebA|ebB ~4.4MB) aliases t2h
  // (12.8MB): dead before k_gemm_mfma writes t2h. WhT outside overlay.
  __half* t2h = (__half*)d_ws;
  int* hist = (int*)d_ws;                      // [M]
  int* partials = hist + M;                    // [<=256] raw block sums
  int* ebA = partials + 256;                   // [E]  (src<<8)|(dst&255), dst-bucketed
  unsigned char* ebB = (unsigned char*)(ebA + E);  // [E] src&255, src-bucketed
  float* dis = (float*)(t2h + (size_t)N * 128);    // [N]
  int* offs = (int*)(dis + N);                 // [N+1]
  int* srcs = offs + (N + 1);                  // [E] pre-scaled src*64
  f16* WhT = (f16*)(srcs + E);                 // [128*128] fp16 B^T

  k_hist<<<NBLK, 256, 0, stream>>>(ei, E, hist, NBLK, NBINS, W, WhT);
  k_scan1<<<NB1, 256, 0, stream>>>(hist, partials, M);
  k_part<<<NBLK, 256, 0, stream>>>(ei, E, hist, partials, NB1, NBLK, NBINS, ebA, ebB);
  k_bucket<<<NBINS, 256, 0, stream>>>(ebA, ebB, hist, partials, NB1, NBLK, NBINS, E,
                                      dis, offs, srcs, N);
  k_gemm_mfma<<<cdiv(N, 64), 256, 0, stream>>>(x, WhT, dis, t2h, N);
  k_gather<<<cdiv(N, 8), 256, 0, stream>>>(offs, srcs, t2h, dis, bias, out, N);
}